// Round 6
// baseline (409.985 us; speedup 1.0000x reference)
//
#include <hip/hip_runtime.h>

#define N_NODES  20000
#define N_EDGES  320000
#define N_GRAPHS 128

__global__ void fill_zero(float* __restrict__ p, int n) {
    int i = blockIdx.x * blockDim.x + threadIdx.x;
    int stride = gridDim.x * blockDim.x;
    for (; i < n; i += stride) p[i] = 0.f;
}

// ---------- f32 GEMM + fused el/er: C[M,N]=A*B, el/er = C . al/ar ----------
template <int BM, int BN, int BK>
__global__ void gemm_el_er(const float* __restrict__ A, const float* __restrict__ B,
                           float* __restrict__ C, const float* __restrict__ al,
                           const float* __restrict__ ar, float* __restrict__ el,
                           float* __restrict__ er, int M, int N, int K, int H, int D) {
    __shared__ float Ast[BK][BM + 4];
    __shared__ float Bs[BK][BN];
    const int tid  = threadIdx.x;
    const int brow = blockIdx.x * BM;
    const int bcol = blockIdx.y * BN;
    const int tr = tid >> 4;          // 0..15
    const int tc = tid & 15;          // 0..15

    float acc[8][4] = {};
    for (int k0 = 0; k0 < K; k0 += BK) {
#pragma unroll
        for (int half = 0; half < 2; ++half) {
            int idx = tid + half * 256;          // 0..511 -> (row, col4)
            int r = idx >> 2, c4 = idx & 3;
            int gr = brow + r;
            float4 v = make_float4(0.f, 0.f, 0.f, 0.f);
            if (gr < M)
                v = *reinterpret_cast<const float4*>(&A[(size_t)gr * K + k0 + c4 * 4]);
            Ast[c4 * 4 + 0][r] = v.x;
            Ast[c4 * 4 + 1][r] = v.y;
            Ast[c4 * 4 + 2][r] = v.z;
            Ast[c4 * 4 + 3][r] = v.w;
        }
        {
            int r = tid >> 4, c4 = tid & 15;     // BK x BN = 256 float4
            *reinterpret_cast<float4*>(&Bs[r][c4 * 4]) =
                *reinterpret_cast<const float4*>(&B[(size_t)(k0 + r) * N + bcol + c4 * 4]);
        }
        __syncthreads();
#pragma unroll
        for (int kk = 0; kk < BK; ++kk) {
            float a[8], b[4];
            *reinterpret_cast<float4*>(&a[0]) = *reinterpret_cast<float4*>(&Ast[kk][tr * 8]);
            *reinterpret_cast<float4*>(&a[4]) = *reinterpret_cast<float4*>(&Ast[kk][tr * 8 + 4]);
            *reinterpret_cast<float4*>(&b[0]) = *reinterpret_cast<float4*>(&Bs[kk][tc * 4]);
#pragma unroll
            for (int m = 0; m < 8; ++m)
#pragma unroll
                for (int n = 0; n < 4; ++n) acc[m][n] += a[m] * b[n];
        }
        __syncthreads();
    }
    // C store
#pragma unroll
    for (int m = 0; m < 8; ++m) {
        int gr = brow + tr * 8 + m;
        if (gr < M) {
            float4 v = make_float4(acc[m][0], acc[m][1], acc[m][2], acc[m][3]);
            *reinterpret_cast<float4*>(&C[(size_t)gr * N + bcol + tc * 4]) = v;
        }
    }
    // fused el/er
    const int hblk = bcol / D;
    float4 alv = *reinterpret_cast<const float4*>(&al[bcol + tc * 4]);
    float4 arv = *reinterpret_cast<const float4*>(&ar[bcol + tc * 4]);
#pragma unroll
    for (int m = 0; m < 8; ++m) {
        float pl = acc[m][0] * alv.x + acc[m][1] * alv.y + acc[m][2] * alv.z + acc[m][3] * alv.w;
        float pr = acc[m][0] * arv.x + acc[m][1] * arv.y + acc[m][2] * arv.z + acc[m][3] * arv.w;
#pragma unroll
        for (int o = 1; o < 16; o <<= 1) {
            pl += __shfl_xor(pl, o);
            pr += __shfl_xor(pr, o);
        }
        int gr = brow + tr * 8 + m;
        if (tc == 0 && gr < M) {
            if (BN == D) {                       // exactly one block per (row, head)
                el[(size_t)gr * H + hblk] = pl;
                er[(size_t)gr * H + hblk] = pr;
            } else {                             // multiple blocks per head
                atomicAdd(&el[(size_t)gr * H + hblk], pl);
                atomicAdd(&er[(size_t)gr * H + hblk], pr);
            }
        }
    }
}

// ---------- CSR build: histogram -> scan -> scatter ----------
__global__ void hist_kernel(const int* __restrict__ dst, int* __restrict__ deg, int E) {
    int e = blockIdx.x * blockDim.x + threadIdx.x;
    if (e >= E) return;
    atomicAdd(&deg[dst[e]], 1);
}

__global__ void scan_kernel(const int* __restrict__ deg, int* __restrict__ rowptr, int n) {
    __shared__ int partial[1024];
    const int t = threadIdx.x;
    const int CH = (n + 1023) / 1024;
    const int base = t * CH;
    int local = 0;
    for (int i = 0; i < CH; ++i)
        if (base + i < n) local += deg[base + i];
    partial[t] = local;
    __syncthreads();
    for (int o = 1; o < 1024; o <<= 1) {
        int v = (t >= o) ? partial[t - o] : 0;
        __syncthreads();
        partial[t] += v;
        __syncthreads();
    }
    int run = (t == 0) ? 0 : partial[t - 1];
    for (int i = 0; i < CH; ++i) {
        if (base + i <= n) rowptr[base + i] = run;
        if (base + i < n) run += deg[base + i];
    }
}

__global__ void scatter_kernel(const int* __restrict__ src, const int* __restrict__ dst,
                               const int* __restrict__ rowptr, int* __restrict__ cursor,
                               int* __restrict__ esrc, int E) {
    int e = blockIdx.x * blockDim.x + threadIdx.x;
    if (e >= E) return;
    int d = dst[e];
    int pos = rowptr[d] + atomicAdd(&cursor[d], 1);
    esrc[pos] = src[e];
}

// ---------- per-node GAT aggregation, XCD column-sliced -------------------
// blockIdx.x & 7 selects a CPS-column slice; with round-robin block->XCD
// mapping, each XCD touches only feat[:, slice] (5.1 MB for layer 1) ->
// L2-resident gathers. CPS: columns per slice; slices = F/CPS = 8.
template <int H, int D, int CPS>
__global__ void node_aggr_v3(const float* __restrict__ feat, const float* __restrict__ el,
                             const float* __restrict__ er, const int* __restrict__ rowptr,
                             const int* __restrict__ esrc, const float* __restrict__ bias,
                             float* __restrict__ rst, int N) {
    constexpr int F   = H * D;
    constexpr int TPN = CPS / 4;          // threads per node (float4 chunks in slice)
    constexpr int NPB = 256 / TPN;        // nodes per block
    const int slice  = blockIdx.x & 7;
    const int nchunk = blockIdx.x >> 3;
    const int tid = threadIdx.x;
    const int n  = nchunk * NPB + tid / TPN;
    if (n >= N) return;
    const int q  = slice * TPN + (tid % TPN);     // float4 index within row
    const int h  = (q * 4) / D;
    const float ern = er[(size_t)n * H + h];
    const int rs = rowptr[n], re = rowptr[n + 1];
    const float* fq = feat + q * 4;
    float dsum = 0.f;
    float ax = 0.f, ay = 0.f, az = 0.f, aw = 0.f;
    int i = rs;
    for (; i + 2 <= re; i += 2) {
        int s0 = esrc[i], s1 = esrc[i + 1];
        float x0 = el[s0 * H + h] + ern;
        float x1 = el[s1 * H + h] + ern;
        x0 = (x0 > 0.f) ? x0 : 0.2f * x0;
        x1 = (x1 > 0.f) ? x1 : 0.2f * x1;
        float w0 = __expf(x0), w1 = __expf(x1);
        float4 f0 = *reinterpret_cast<const float4*>(fq + (size_t)s0 * F);
        float4 f1 = *reinterpret_cast<const float4*>(fq + (size_t)s1 * F);
        dsum += w0 + w1;
        ax += w0 * f0.x + w1 * f1.x;
        ay += w0 * f0.y + w1 * f1.y;
        az += w0 * f0.z + w1 * f1.z;
        aw += w0 * f0.w + w1 * f1.w;
    }
    if (i < re) {
        int s = esrc[i];
        float x = el[s * H + h] + ern;
        x = (x > 0.f) ? x : 0.2f * x;
        float w = __expf(x);
        float4 f = *reinterpret_cast<const float4*>(fq + (size_t)s * F);
        dsum += w;
        ax += w * f.x; ay += w * f.y; az += w * f.z; aw += w * f.w;
    }
    float inv = (re > rs) ? 1.f / dsum : 0.f;
    float4 b = *reinterpret_cast<const float4*>(bias + q * 4);
    float4 o = make_float4(ax * inv + b.x, ay * inv + b.y, az * inv + b.z, aw * inv + b.w);
    *reinterpret_cast<float4*>(rst + (size_t)n * F + q * 4) = o;
}

// ---------- per-graph mean pooling (gid is SORTED -> segmented reduce) -----
__global__ void graph_start_kernel(const int* __restrict__ gid, int* __restrict__ start,
                                   int N, int G) {
    int g = blockIdx.x * blockDim.x + threadIdx.x;
    if (g > G) return;
    if (g == G) { start[G] = N; return; }
    int lo = 0, hi = N;                     // lower_bound(gid, g)
    while (lo < hi) {
        int mid = (lo + hi) >> 1;
        if (gid[mid] < g) lo = mid + 1; else hi = mid;
    }
    start[g] = lo;
}

// one block per graph; thread d accumulates over the graph's node range.
__global__ void seg_pool_kernel(const float* __restrict__ h, const int* __restrict__ start,
                                float* __restrict__ out, int D) {
    int g = blockIdx.x;
    int d = threadIdx.x;
    int s = start[g], e = start[g + 1];
    float acc = 0.f;
    for (int n = s; n < e; ++n) acc += h[(size_t)n * D + d];
    out[(size_t)g * D + d] = acc / fmaxf((float)(e - s), 1.f);
}

extern "C" void kernel_launch(void* const* d_in, const int* in_sizes, int n_in,
                              void* d_out, int out_size, void* d_ws, size_t ws_size,
                              hipStream_t stream) {
    const float* x   = (const float*)d_in[0];
    const float* W1  = (const float*)d_in[1];
    const float* al1 = (const float*)d_in[2];
    const float* ar1 = (const float*)d_in[3];
    const float* b1  = (const float*)d_in[4];
    const float* W2  = (const float*)d_in[5];
    const float* al2 = (const float*)d_in[6];
    const float* ar2 = (const float*)d_in[7];
    const float* b2  = (const float*)d_in[8];
    const int* src   = (const int*)d_in[9];
    const int* dst   = (const int*)d_in[10];
    const int* gid   = (const int*)d_in[11];
    float* out = (float*)d_out;

    float* ws = (float*)d_ws;
    size_t off = 0;
    // ---- zero-initialized region ----
    int*   deg    = (int*)(ws + off); off += N_NODES;
    int*   cursor = (int*)(ws + off); off += N_NODES;
    float* el2    = ws + off;         off += N_NODES;   // atomicAdd targets
    float* er2    = ws + off;         off += N_NODES;
    const size_t zeroN = off;
    // ---- write-before-read region (16B-aligned chunks) ----
    int* rowptr = (int*)(ws + off); off += N_NODES + 4;
    int* gstart = (int*)(ws + off); off += N_GRAPHS + 4;
    int* esrc   = (int*)(ws + off); off += N_EDGES;
    float* feat1 = ws + off; off += (size_t)N_NODES * 512;
    float* el1   = ws + off; off += (size_t)N_NODES * 8;
    float* er1   = ws + off; off += (size_t)N_NODES * 8;
    float* rst1  = ws + off; off += (size_t)N_NODES * 512;
    float* rst2  = ws + off; off += (size_t)N_NODES * 128;
    float* feat2 = feat1;  // feat1 dead once layer-1 aggregation is done

    fill_zero<<<512, 256, 0, stream>>>(ws, (int)zeroN);

    // ---- CSR build (shared by both layers) + graph segment starts ----
    hist_kernel<<<(N_EDGES + 255) / 256, 256, 0, stream>>>(dst, deg, N_EDGES);
    scan_kernel<<<1, 1024, 0, stream>>>(deg, rowptr, N_NODES);
    scatter_kernel<<<(N_EDGES + 255) / 256, 256, 0, stream>>>(src, dst, rowptr, cursor, esrc, N_EDGES);
    graph_start_kernel<<<1, 256, 0, stream>>>(gid, gstart, N_NODES, N_GRAPHS);

    // ===== layer 1: H=8, D=64 =====
    dim3 g1((N_NODES + 127) / 128, 512 / 64);
    gemm_el_er<128, 64, 16><<<g1, 256, 0, stream>>>(
        x, W1, feat1, al1, ar1, el1, er1, N_NODES, 512, 256, 8, 64);
    // slices=8 (one head each), 16 nodes/block -> 1250*8 blocks
    node_aggr_v3<8, 64, 64><<<(N_NODES / 16) * 8, 256, 0, stream>>>(
        feat1, el1, er1, rowptr, esrc, b1, rst1, N_NODES);

    // ===== layer 2: H=1, D=128 =====
    dim3 g2((N_NODES + 127) / 128, 128 / 64);
    gemm_el_er<128, 64, 16><<<g2, 256, 0, stream>>>(
        rst1, W2, feat2, al2, ar2, el2, er2, N_NODES, 128, 512, 1, 128);
    // slices=8 (16 cols each), 64 nodes/block -> ceil(20000/64)*8 blocks
    node_aggr_v3<1, 128, 16><<<((N_NODES + 63) / 64) * 8, 256, 0, stream>>>(
        feat2, el2, er2, rowptr, esrc, b2, rst2, N_NODES);

    // ===== readout: per-graph mean (segmented, no atomics) =====
    seg_pool_kernel<<<N_GRAPHS, 128, 0, stream>>>(rst2, gstart, out, 128);
}

// Round 7
// 361.402 us; speedup vs baseline: 1.1344x; 1.1344x over previous
//
#include <hip/hip_runtime.h>
#include <hip/hip_fp16.h>

#define N_NODES  20000
#define N_EDGES  320000
#define N_GRAPHS 128

__global__ void fill_zero(float* __restrict__ p, int n) {
    int i = blockIdx.x * blockDim.x + threadIdx.x;
    int stride = gridDim.x * blockDim.x;
    for (; i < n; i += stride) p[i] = 0.f;
}

// ---------- f32 GEMM + fused el/er; feat output stored as fp16 ------------
// C[M,N] = A*B (stored __half), el/er = (C . al/ar) per (row, head), f32.
template <int BM, int BN, int BK>
__global__ void gemm_el_er(const float* __restrict__ A, const float* __restrict__ B,
                           __half* __restrict__ C, const float* __restrict__ al,
                           const float* __restrict__ ar, float* __restrict__ el,
                           float* __restrict__ er, int M, int N, int K, int H, int D) {
    __shared__ float Ast[BK][BM + 4];
    __shared__ float Bs[BK][BN];
    const int tid  = threadIdx.x;
    const int brow = blockIdx.x * BM;
    const int bcol = blockIdx.y * BN;
    const int tr = tid >> 4;          // 0..15
    const int tc = tid & 15;          // 0..15

    float acc[8][4] = {};
    for (int k0 = 0; k0 < K; k0 += BK) {
#pragma unroll
        for (int half_ = 0; half_ < 2; ++half_) {
            int idx = tid + half_ * 256;         // 0..511 -> (row, col4)
            int r = idx >> 2, c4 = idx & 3;
            int gr = brow + r;
            float4 v = make_float4(0.f, 0.f, 0.f, 0.f);
            if (gr < M)
                v = *reinterpret_cast<const float4*>(&A[(size_t)gr * K + k0 + c4 * 4]);
            Ast[c4 * 4 + 0][r] = v.x;
            Ast[c4 * 4 + 1][r] = v.y;
            Ast[c4 * 4 + 2][r] = v.z;
            Ast[c4 * 4 + 3][r] = v.w;
        }
        {
            int r = tid >> 4, c4 = tid & 15;     // BK x BN = 256 float4
            *reinterpret_cast<float4*>(&Bs[r][c4 * 4]) =
                *reinterpret_cast<const float4*>(&B[(size_t)(k0 + r) * N + bcol + c4 * 4]);
        }
        __syncthreads();
#pragma unroll
        for (int kk = 0; kk < BK; ++kk) {
            float a[8], b[4];
            *reinterpret_cast<float4*>(&a[0]) = *reinterpret_cast<float4*>(&Ast[kk][tr * 8]);
            *reinterpret_cast<float4*>(&a[4]) = *reinterpret_cast<float4*>(&Ast[kk][tr * 8 + 4]);
            *reinterpret_cast<float4*>(&b[0]) = *reinterpret_cast<float4*>(&Bs[kk][tc * 4]);
#pragma unroll
            for (int m = 0; m < 8; ++m)
#pragma unroll
                for (int n = 0; n < 4; ++n) acc[m][n] += a[m] * b[n];
        }
        __syncthreads();
    }
    // C store (fp16, 8B per thread-row)
#pragma unroll
    for (int m = 0; m < 8; ++m) {
        int gr = brow + tr * 8 + m;
        if (gr < M) {
            union { __half2 h[2]; uint2 u; } pk;
            pk.h[0] = __floats2half2_rn(acc[m][0], acc[m][1]);
            pk.h[1] = __floats2half2_rn(acc[m][2], acc[m][3]);
            *reinterpret_cast<uint2*>(&C[(size_t)gr * N + bcol + tc * 4]) = pk.u;
        }
    }
    // fused el/er (f32 accuracy)
    const int hblk = bcol / D;
    float4 alv = *reinterpret_cast<const float4*>(&al[bcol + tc * 4]);
    float4 arv = *reinterpret_cast<const float4*>(&ar[bcol + tc * 4]);
#pragma unroll
    for (int m = 0; m < 8; ++m) {
        float pl = acc[m][0] * alv.x + acc[m][1] * alv.y + acc[m][2] * alv.z + acc[m][3] * alv.w;
        float pr = acc[m][0] * arv.x + acc[m][1] * arv.y + acc[m][2] * arv.z + acc[m][3] * arv.w;
#pragma unroll
        for (int o = 1; o < 16; o <<= 1) {
            pl += __shfl_xor(pl, o);
            pr += __shfl_xor(pr, o);
        }
        int gr = brow + tr * 8 + m;
        if (tc == 0 && gr < M) {
            if (BN == D) {                       // exactly one block per (row, head)
                el[(size_t)gr * H + hblk] = pl;
                er[(size_t)gr * H + hblk] = pr;
            } else {                             // multiple blocks per head
                atomicAdd(&el[(size_t)gr * H + hblk], pl);
                atomicAdd(&er[(size_t)gr * H + hblk], pr);
            }
        }
    }
}

// ---------- CSR build: histogram -> scan -> scatter ----------
__global__ void hist_kernel(const int* __restrict__ dst, int* __restrict__ deg, int E) {
    int e = blockIdx.x * blockDim.x + threadIdx.x;
    if (e >= E) return;
    atomicAdd(&deg[dst[e]], 1);
}

__global__ void scan_kernel(const int* __restrict__ deg, int* __restrict__ rowptr, int n) {
    __shared__ int partial[1024];
    const int t = threadIdx.x;
    const int CH = (n + 1023) / 1024;
    const int base = t * CH;
    int local = 0;
    for (int i = 0; i < CH; ++i)
        if (base + i < n) local += deg[base + i];
    partial[t] = local;
    __syncthreads();
    for (int o = 1; o < 1024; o <<= 1) {
        int v = (t >= o) ? partial[t - o] : 0;
        __syncthreads();
        partial[t] += v;
        __syncthreads();
    }
    int run = (t == 0) ? 0 : partial[t - 1];
    for (int i = 0; i < CH; ++i) {
        if (base + i <= n) rowptr[base + i] = run;
        if (base + i < n) run += deg[base + i];
    }
}

__global__ void scatter_kernel(const int* __restrict__ src, const int* __restrict__ dst,
                               const int* __restrict__ rowptr, int* __restrict__ cursor,
                               int* __restrict__ esrc, int E) {
    int e = blockIdx.x * blockDim.x + threadIdx.x;
    if (e >= E) return;
    int d = dst[e];
    int pos = rowptr[d] + atomicAdd(&cursor[d], 1);
    esrc[pos] = src[e];
}

// ---------- per-node GAT aggregation, fp16 payload, XCD column-sliced ------
// blockIdx.x & 7 -> column slice; per-XCD footprint = N*CPS*2B (2.56 MB for
// layer 1, 640 KB for layer 2) -> L2-resident. Weights stay f32.
template <int H, int D, int CPS>
__global__ void node_aggr_h(const __half* __restrict__ feat, const float* __restrict__ el,
                            const float* __restrict__ er, const int* __restrict__ rowptr,
                            const int* __restrict__ esrc, const float* __restrict__ bias,
                            float* __restrict__ rst, int N) {
    constexpr int F   = H * D;
    constexpr int TPN = CPS / 4;          // each thread owns 4 columns (8B gathers)
    constexpr int NPB = 256 / TPN;
    const int slice  = blockIdx.x & 7;
    const int nchunk = blockIdx.x >> 3;
    const int tid = threadIdx.x;
    const int n  = nchunk * NPB + tid / TPN;
    if (n >= N) return;
    const int col = (slice * TPN + (tid % TPN)) * 4;
    const int h   = col / D;
    const float ern = er[(size_t)n * H + h];
    const int rs = rowptr[n], re = rowptr[n + 1];
    const __half* fq = feat + col;
    float dsum = 0.f;
    float ax = 0.f, ay = 0.f, az = 0.f, aw = 0.f;
    int i = rs;
    for (; i + 2 <= re; i += 2) {
        int s0 = esrc[i], s1 = esrc[i + 1];
        float x0 = el[s0 * H + h] + ern;
        float x1 = el[s1 * H + h] + ern;
        x0 = (x0 > 0.f) ? x0 : 0.2f * x0;
        x1 = (x1 > 0.f) ? x1 : 0.2f * x1;
        float w0 = __expf(x0), w1 = __expf(x1);
        union { uint2 u; __half2 h2[2]; } r0, r1;
        r0.u = *reinterpret_cast<const uint2*>(fq + (size_t)s0 * F);
        r1.u = *reinterpret_cast<const uint2*>(fq + (size_t)s1 * F);
        float2 a0 = __half22float2(r0.h2[0]), b0 = __half22float2(r0.h2[1]);
        float2 a1 = __half22float2(r1.h2[0]), b1 = __half22float2(r1.h2[1]);
        dsum += w0 + w1;
        ax += w0 * a0.x + w1 * a1.x;
        ay += w0 * a0.y + w1 * a1.y;
        az += w0 * b0.x + w1 * b1.x;
        aw += w0 * b0.y + w1 * b1.y;
    }
    if (i < re) {
        int s = esrc[i];
        float x = el[s * H + h] + ern;
        x = (x > 0.f) ? x : 0.2f * x;
        float w = __expf(x);
        union { uint2 u; __half2 h2[2]; } r;
        r.u = *reinterpret_cast<const uint2*>(fq + (size_t)s * F);
        float2 a = __half22float2(r.h2[0]), b = __half22float2(r.h2[1]);
        dsum += w;
        ax += w * a.x; ay += w * a.y; az += w * b.x; aw += w * b.y;
    }
    float inv = (re > rs) ? 1.f / dsum : 0.f;
    float4 bv = *reinterpret_cast<const float4*>(bias + col);
    float4 o = make_float4(ax * inv + bv.x, ay * inv + bv.y, az * inv + bv.z, aw * inv + bv.w);
    *reinterpret_cast<float4*>(rst + (size_t)n * F + col) = o;
}

// ---------- per-graph mean pooling (gid is SORTED -> segmented reduce) -----
__global__ void graph_start_kernel(const int* __restrict__ gid, int* __restrict__ start,
                                   int N, int G) {
    int g = blockIdx.x * blockDim.x + threadIdx.x;
    if (g > G) return;
    if (g == G) { start[G] = N; return; }
    int lo = 0, hi = N;                     // lower_bound(gid, g)
    while (lo < hi) {
        int mid = (lo + hi) >> 1;
        if (gid[mid] < g) lo = mid + 1; else hi = mid;
    }
    start[g] = lo;
}

__global__ void seg_pool_kernel(const float* __restrict__ h, const int* __restrict__ start,
                                float* __restrict__ out, int D) {
    int g = blockIdx.x;
    int d = threadIdx.x;
    int s = start[g], e = start[g + 1];
    float acc = 0.f;
    for (int n = s; n < e; ++n) acc += h[(size_t)n * D + d];
    out[(size_t)g * D + d] = acc / fmaxf((float)(e - s), 1.f);
}

extern "C" void kernel_launch(void* const* d_in, const int* in_sizes, int n_in,
                              void* d_out, int out_size, void* d_ws, size_t ws_size,
                              hipStream_t stream) {
    const float* x   = (const float*)d_in[0];
    const float* W1  = (const float*)d_in[1];
    const float* al1 = (const float*)d_in[2];
    const float* ar1 = (const float*)d_in[3];
    const float* b1  = (const float*)d_in[4];
    const float* W2  = (const float*)d_in[5];
    const float* al2 = (const float*)d_in[6];
    const float* ar2 = (const float*)d_in[7];
    const float* b2  = (const float*)d_in[8];
    const int* src   = (const int*)d_in[9];
    const int* dst   = (const int*)d_in[10];
    const int* gid   = (const int*)d_in[11];
    float* out = (float*)d_out;

    float* ws = (float*)d_ws;
    size_t off = 0;
    // ---- zero-initialized region ----
    int*   deg    = (int*)(ws + off); off += N_NODES;
    int*   cursor = (int*)(ws + off); off += N_NODES;
    float* el2    = ws + off;         off += N_NODES;   // atomicAdd targets
    float* er2    = ws + off;         off += N_NODES;
    const size_t zeroN = off;
    // ---- write-before-read region (16B-aligned chunks) ----
    int* rowptr = (int*)(ws + off); off += N_NODES + 4;
    int* gstart = (int*)(ws + off); off += N_GRAPHS + 4;
    int* esrc   = (int*)(ws + off); off += N_EDGES;
    __half* feat1 = (__half*)(ws + off); off += (size_t)N_NODES * 256;  // 512 halves
    float*  el1   = ws + off; off += (size_t)N_NODES * 8;
    float*  er1   = ws + off; off += (size_t)N_NODES * 8;
    float*  rst1  = ws + off; off += (size_t)N_NODES * 512;
    __half* feat2 = (__half*)(ws + off); off += (size_t)N_NODES * 64;   // 128 halves
    float*  rst2  = ws + off; off += (size_t)N_NODES * 128;

    fill_zero<<<512, 256, 0, stream>>>(ws, (int)zeroN);

    // ---- CSR build (shared by both layers) + graph segment starts ----
    hist_kernel<<<(N_EDGES + 255) / 256, 256, 0, stream>>>(dst, deg, N_EDGES);
    scan_kernel<<<1, 1024, 0, stream>>>(deg, rowptr, N_NODES);
    scatter_kernel<<<(N_EDGES + 255) / 256, 256, 0, stream>>>(src, dst, rowptr, cursor, esrc, N_EDGES);
    graph_start_kernel<<<1, 256, 0, stream>>>(gid, gstart, N_NODES, N_GRAPHS);

    // ===== layer 1: H=8, D=64 =====
    dim3 g1((N_NODES + 127) / 128, 512 / 64);
    gemm_el_er<128, 64, 16><<<g1, 256, 0, stream>>>(
        x, W1, feat1, al1, ar1, el1, er1, N_NODES, 512, 256, 8, 64);
    // slices=8 (one head each, 2.56 MB/slice), TPN=16, 16 nodes/block
    node_aggr_h<8, 64, 64><<<(N_NODES / 16) * 8, 256, 0, stream>>>(
        feat1, el1, er1, rowptr, esrc, b1, rst1, N_NODES);

    // ===== layer 2: H=1, D=128 =====
    dim3 g2((N_NODES + 127) / 128, 128 / 64);
    gemm_el_er<128, 64, 16><<<g2, 256, 0, stream>>>(
        rst1, W2, feat2, al2, ar2, el2, er2, N_NODES, 128, 512, 1, 128);
    // slices=8 (16 cols each, 640 KB/slice), TPN=4, 64 nodes/block
    node_aggr_h<1, 128, 16><<<((N_NODES + 63) / 64) * 8, 256, 0, stream>>>(
        feat2, el2, er2, rowptr, esrc, b2, rst2, N_NODES);

    // ===== readout: per-graph mean (segmented, no atomics) =====
    seg_pool_kernel<<<N_GRAPHS, 128, 0, stream>>>(rst2, gstart, out, 128);
}

// Round 8
// 280.476 us; speedup vs baseline: 1.4617x; 1.2885x over previous
//
#include <hip/hip_runtime.h>
#include <hip/hip_fp16.h>

#define N_NODES  20000
#define N_EDGES  320000
#define N_GRAPHS 128

typedef _Float16 half8 __attribute__((ext_vector_type(8)));
typedef float    f32x4 __attribute__((ext_vector_type(4)));

__global__ void fill_zero(float* __restrict__ p, int n) {
    int i = blockIdx.x * blockDim.x + threadIdx.x;
    int stride = gridDim.x * blockDim.x;
    for (; i < n; i += stride) p[i] = 0.f;
}

// ---------- f32 -> fp16 convert (4 elems/thread) ----------
__global__ void f32_to_h(const float* __restrict__ in, __half* __restrict__ o, int n4) {
    int i = blockIdx.x * blockDim.x + threadIdx.x;
    if (i >= n4) return;
    float4 v = *reinterpret_cast<const float4*>(&in[i * 4]);
    union { __half2 h2[2]; uint2 u; } pk;
    pk.h2[0] = __floats2half2_rn(v.x, v.y);
    pk.h2[1] = __floats2half2_rn(v.z, v.w);
    *reinterpret_cast<uint2*>(&o[i * 4]) = pk.u;
}

// ---------- W[R,C] f32 -> WT[C,R] fp16 ----------
__global__ void transpose_h(const float* __restrict__ W, __half* __restrict__ WT,
                            int R, int C) {
    int i = blockIdx.x * blockDim.x + threadIdx.x;
    if (i >= R * C) return;
    int r = i / C, c = i - r * C;
    WT[(size_t)c * R + r] = __float2half(W[i]);
}

// ---------- MFMA fp16 GEMM + fused el/er ----------
// A [M,K] fp16 row-major, BT [N,K] fp16 row-major (pre-transposed weights).
// C [M,N] fp16. el/er [M,H] f32 from f32 accumulators.
// 4 waves; wave (wr,wc) owns WM x WN. LDS XOR-swizzled (both sides).
template <int BM, int BN, int WM, int WN, int H, int D>
__global__ __launch_bounds__(256) void gemm_mfma(
        const __half* __restrict__ A, const __half* __restrict__ BT,
        __half* __restrict__ C, const float* __restrict__ al,
        const float* __restrict__ ar, float* __restrict__ el,
        float* __restrict__ er, int Mm, int Nn, int Kk) {
    constexpr int BK  = 32;
    constexpr int MFR = WM / 16, NFR = WN / 16;
    constexpr int WCOLS = BN / WN;
    __shared__ __align__(16) __half As[BM * BK];
    __shared__ __align__(16) __half Bs[BN * BK];
    const int tid  = threadIdx.x;
    const int w    = tid >> 6, lane = tid & 63;
    const int wr   = w / WCOLS, wc = w % WCOLS;
    const int brow = blockIdx.x * BM;
    const int bcol = blockIdx.y * BN;
    const int lr   = lane & 15;
    const int lk   = (lane >> 4) * 8;

    f32x4 acc[MFR][NFR] = {};

    for (int k0 = 0; k0 < Kk; k0 += BK) {
        // stage A (BM x 32 halves), 16B chunks, swizzled dest
        for (int c = tid; c < BM * 4; c += 256) {
            int r = c >> 2, ko = (c & 3) * 8;
            int gr = brow + r; if (gr >= Mm) gr = Mm - 1;
            int off = (r * BK + ko) ^ ((r & 7) << 3);
            *reinterpret_cast<uint4*>(&As[off]) =
                *reinterpret_cast<const uint4*>(&A[(size_t)gr * Kk + k0 + ko]);
        }
        // stage BT (BN x 32 halves)
        for (int c = tid; c < BN * 4; c += 256) {
            int r = c >> 2, ko = (c & 3) * 8;
            int off = (r * BK + ko) ^ ((r & 7) << 3);
            *reinterpret_cast<uint4*>(&Bs[off]) =
                *reinterpret_cast<const uint4*>(&BT[(size_t)(bcol + r) * Kk + k0 + ko]);
        }
        __syncthreads();
        half8 af[MFR], bf[NFR];
#pragma unroll
        for (int m = 0; m < MFR; ++m) {
            int r = wr * WM + m * 16 + lr;
            af[m] = *reinterpret_cast<const half8*>(&As[(r * BK + lk) ^ ((r & 7) << 3)]);
        }
#pragma unroll
        for (int n = 0; n < NFR; ++n) {
            int r = wc * WN + n * 16 + lr;
            bf[n] = *reinterpret_cast<const half8*>(&Bs[(r * BK + lk) ^ ((r & 7) << 3)]);
        }
#pragma unroll
        for (int m = 0; m < MFR; ++m)
#pragma unroll
            for (int n = 0; n < NFR; ++n)
                acc[m][n] = __builtin_amdgcn_mfma_f32_16x16x32_f16(af[m], bf[n], acc[m][n], 0, 0, 0);
        __syncthreads();
    }

    // ---- C store (fp16) ----
#pragma unroll
    for (int m = 0; m < MFR; ++m) {
        int r0 = brow + wr * WM + m * 16 + ((lane >> 4) << 2);
#pragma unroll
        for (int n = 0; n < NFR; ++n) {
            int cc = bcol + wc * WN + n * 16 + lr;
#pragma unroll
            for (int g = 0; g < 4; ++g)
                if (r0 + g < Mm) C[(size_t)(r0 + g) * Nn + cc] = __float2half(acc[m][n][g]);
        }
    }
    // ---- fused el/er ----
    const int h = (bcol + wc * WN) / D;
    float alv[NFR], arv[NFR];
#pragma unroll
    for (int n = 0; n < NFR; ++n) {
        alv[n] = al[bcol + wc * WN + n * 16 + lr];
        arv[n] = ar[bcol + wc * WN + n * 16 + lr];
    }
#pragma unroll
    for (int m = 0; m < MFR; ++m) {
#pragma unroll
        for (int g = 0; g < 4; ++g) {
            float pl = 0.f, pr = 0.f;
#pragma unroll
            for (int n = 0; n < NFR; ++n) {
                pl += acc[m][n][g] * alv[n];
                pr += acc[m][n][g] * arv[n];
            }
            pl += __shfl_xor(pl, 1); pl += __shfl_xor(pl, 2);
            pl += __shfl_xor(pl, 4); pl += __shfl_xor(pl, 8);
            pr += __shfl_xor(pr, 1); pr += __shfl_xor(pr, 2);
            pr += __shfl_xor(pr, 4); pr += __shfl_xor(pr, 8);
            int gr = brow + wr * WM + m * 16 + ((lane >> 4) << 2) + g;
            if (lr == 0 && gr < Mm) {
                if constexpr (WN == D) {
                    el[(size_t)gr * H + h] = pl;
                    er[(size_t)gr * H + h] = pr;
                } else {
                    atomicAdd(&el[(size_t)gr * H + h], pl);
                    atomicAdd(&er[(size_t)gr * H + h], pr);
                }
            }
        }
    }
}

// ---------- CSR build: histogram -> scan -> scatter ----------
__global__ void hist_kernel(const int* __restrict__ dst, int* __restrict__ deg, int E) {
    int e = blockIdx.x * blockDim.x + threadIdx.x;
    if (e >= E) return;
    atomicAdd(&deg[dst[e]], 1);
}

__global__ void scan_kernel(const int* __restrict__ deg, int* __restrict__ rowptr, int n) {
    __shared__ int partial[1024];
    const int t = threadIdx.x;
    const int CH = (n + 1023) / 1024;
    const int base = t * CH;
    int local = 0;
    for (int i = 0; i < CH; ++i)
        if (base + i < n) local += deg[base + i];
    partial[t] = local;
    __syncthreads();
    for (int o = 1; o < 1024; o <<= 1) {
        int v = (t >= o) ? partial[t - o] : 0;
        __syncthreads();
        partial[t] += v;
        __syncthreads();
    }
    int run = (t == 0) ? 0 : partial[t - 1];
    for (int i = 0; i < CH; ++i) {
        if (base + i <= n) rowptr[base + i] = run;
        if (base + i < n) run += deg[base + i];
    }
}

__global__ void scatter_kernel(const int* __restrict__ src, const int* __restrict__ dst,
                               const int* __restrict__ rowptr, int* __restrict__ cursor,
                               int* __restrict__ esrc, int E) {
    int e = blockIdx.x * blockDim.x + threadIdx.x;
    if (e >= E) return;
    int d = dst[e];
    int pos = rowptr[d] + atomicAdd(&cursor[d], 1);
    esrc[pos] = src[e];
}

// ---------- per-node GAT aggregation, fp16 payload, XCD column-sliced ------
template <int H, int D, int CPS, bool HOUT>
__global__ void node_aggr_h(const __half* __restrict__ feat, const float* __restrict__ el,
                            const float* __restrict__ er, const int* __restrict__ rowptr,
                            const int* __restrict__ esrc, const float* __restrict__ bias,
                            void* __restrict__ rst_, int N) {
    constexpr int F   = H * D;
    constexpr int TPN = CPS / 4;
    constexpr int NPB = 256 / TPN;
    const int slice  = blockIdx.x & 7;
    const int nchunk = blockIdx.x >> 3;
    const int tid = threadIdx.x;
    const int n  = nchunk * NPB + tid / TPN;
    if (n >= N) return;
    const int col = (slice * TPN + (tid % TPN)) * 4;
    const int h   = col / D;
    const float ern = er[(size_t)n * H + h];
    const int rs = rowptr[n], re = rowptr[n + 1];
    const __half* fq = feat + col;
    float dsum = 0.f;
    float ax = 0.f, ay = 0.f, az = 0.f, aw = 0.f;
    int i = rs;
    for (; i + 2 <= re; i += 2) {
        int s0 = esrc[i], s1 = esrc[i + 1];
        float x0 = el[s0 * H + h] + ern;
        float x1 = el[s1 * H + h] + ern;
        x0 = (x0 > 0.f) ? x0 : 0.2f * x0;
        x1 = (x1 > 0.f) ? x1 : 0.2f * x1;
        float w0 = __expf(x0), w1 = __expf(x1);
        union { uint2 u; __half2 h2[2]; } r0, r1;
        r0.u = *reinterpret_cast<const uint2*>(fq + (size_t)s0 * F);
        r1.u = *reinterpret_cast<const uint2*>(fq + (size_t)s1 * F);
        float2 a0 = __half22float2(r0.h2[0]), b0 = __half22float2(r0.h2[1]);
        float2 a1 = __half22float2(r1.h2[0]), b1 = __half22float2(r1.h2[1]);
        dsum += w0 + w1;
        ax += w0 * a0.x + w1 * a1.x;
        ay += w0 * a0.y + w1 * a1.y;
        az += w0 * b0.x + w1 * b1.x;
        aw += w0 * b0.y + w1 * b1.y;
    }
    if (i < re) {
        int s = esrc[i];
        float x = el[s * H + h] + ern;
        x = (x > 0.f) ? x : 0.2f * x;
        float wg = __expf(x);
        union { uint2 u; __half2 h2[2]; } r;
        r.u = *reinterpret_cast<const uint2*>(fq + (size_t)s * F);
        float2 a = __half22float2(r.h2[0]), b = __half22float2(r.h2[1]);
        dsum += wg;
        ax += wg * a.x; ay += wg * a.y; az += wg * b.x; aw += wg * b.y;
    }
    float inv = (re > rs) ? 1.f / dsum : 0.f;
    float4 bv = *reinterpret_cast<const float4*>(bias + col);
    float o0 = ax * inv + bv.x, o1 = ay * inv + bv.y;
    float o2 = az * inv + bv.z, o3 = aw * inv + bv.w;
    if constexpr (HOUT) {
        union { __half2 h2[2]; uint2 u; } pk;
        pk.h2[0] = __floats2half2_rn(o0, o1);
        pk.h2[1] = __floats2half2_rn(o2, o3);
        *reinterpret_cast<uint2*>((__half*)rst_ + (size_t)n * F + col) = pk.u;
    } else {
        *reinterpret_cast<float4*>((float*)rst_ + (size_t)n * F + col) =
            make_float4(o0, o1, o2, o3);
    }
}

// ---------- per-graph mean pooling (gid sorted -> segmented reduce) ----------
__global__ void graph_start_kernel(const int* __restrict__ gid, int* __restrict__ start,
                                   int N, int G) {
    int g = blockIdx.x * blockDim.x + threadIdx.x;
    if (g > G) return;
    if (g == G) { start[G] = N; return; }
    int lo = 0, hi = N;
    while (lo < hi) {
        int mid = (lo + hi) >> 1;
        if (gid[mid] < g) lo = mid + 1; else hi = mid;
    }
    start[g] = lo;
}

__global__ void seg_pool_kernel(const float* __restrict__ h, const int* __restrict__ start,
                                float* __restrict__ out, int D) {
    int g = blockIdx.x;
    int d = threadIdx.x;
    int s = start[g], e = start[g + 1];
    float acc = 0.f;
    for (int n = s; n < e; ++n) acc += h[(size_t)n * D + d];
    out[(size_t)g * D + d] = acc / fmaxf((float)(e - s), 1.f);
}

extern "C" void kernel_launch(void* const* d_in, const int* in_sizes, int n_in,
                              void* d_out, int out_size, void* d_ws, size_t ws_size,
                              hipStream_t stream) {
    const float* x   = (const float*)d_in[0];
    const float* W1  = (const float*)d_in[1];
    const float* al1 = (const float*)d_in[2];
    const float* ar1 = (const float*)d_in[3];
    const float* b1  = (const float*)d_in[4];
    const float* W2  = (const float*)d_in[5];
    const float* al2 = (const float*)d_in[6];
    const float* ar2 = (const float*)d_in[7];
    const float* b2  = (const float*)d_in[8];
    const int* src   = (const int*)d_in[9];
    const int* dst   = (const int*)d_in[10];
    const int* gid   = (const int*)d_in[11];
    float* out = (float*)d_out;

    float* ws = (float*)d_ws;
    size_t off = 0;
    // ---- zero-initialized region ----
    int*   deg    = (int*)(ws + off); off += N_NODES;
    int*   cursor = (int*)(ws + off); off += N_NODES;
    float* el2    = ws + off;         off += N_NODES;   // atomic targets
    float* er2    = ws + off;         off += N_NODES;
    const size_t zeroN = off;
    // ---- write-before-read region (16B-aligned chunks) ----
    int* rowptr = (int*)(ws + off); off += N_NODES + 4;
    int* gstart = (int*)(ws + off); off += N_GRAPHS + 4;
    int* esrc   = (int*)(ws + off); off += N_EDGES;
    __half* xh     = (__half*)(ws + off); off += (size_t)N_NODES * 128;   // 256 halves
    __half* w1t    = (__half*)(ws + off); off += 512 * 256 / 2;
    __half* w2t    = (__half*)(ws + off); off += 128 * 512 / 2;
    __half* feat1h = (__half*)(ws + off); off += (size_t)N_NODES * 256;   // 512 halves
    float*  el1    = ws + off; off += (size_t)N_NODES * 8;
    float*  er1    = ws + off; off += (size_t)N_NODES * 8;
    __half* rst1h  = (__half*)(ws + off); off += (size_t)N_NODES * 256;   // 512 halves
    __half* feat2h = (__half*)(ws + off); off += (size_t)N_NODES * 64;    // 128 halves
    float*  rst2   = ws + off; off += (size_t)N_NODES * 128;

    fill_zero<<<512, 256, 0, stream>>>(ws, (int)zeroN);

    // ---- CSR build + graph segment starts + fp16 conversions ----
    hist_kernel<<<(N_EDGES + 255) / 256, 256, 0, stream>>>(dst, deg, N_EDGES);
    scan_kernel<<<1, 1024, 0, stream>>>(deg, rowptr, N_NODES);
    scatter_kernel<<<(N_EDGES + 255) / 256, 256, 0, stream>>>(src, dst, rowptr, cursor, esrc, N_EDGES);
    graph_start_kernel<<<1, 256, 0, stream>>>(gid, gstart, N_NODES, N_GRAPHS);
    f32_to_h<<<(N_NODES * 256 / 4 + 255) / 256, 256, 0, stream>>>(x, xh, N_NODES * 256 / 4);
    transpose_h<<<(256 * 512 + 255) / 256, 256, 0, stream>>>(W1, w1t, 256, 512);
    transpose_h<<<(512 * 128 + 255) / 256, 256, 0, stream>>>(W2, w2t, 512, 128);

    // ===== layer 1: H=8, D=64; MFMA GEMM [20000,256]x[256,512] =====
    dim3 g1((N_NODES + 127) / 128, 512 / 128);
    gemm_mfma<128, 128, 64, 64, 8, 64><<<g1, 256, 0, stream>>>(
        xh, w1t, feat1h, al1, ar1, el1, er1, N_NODES, 512, 256);
    node_aggr_h<8, 64, 64, true><<<(N_NODES / 16) * 8, 256, 0, stream>>>(
        feat1h, el1, er1, rowptr, esrc, b1, rst1h, N_NODES);

    // ===== layer 2: H=1, D=128; MFMA GEMM [20000,512]x[512,128] =====
    dim3 g2((N_NODES + 63) / 64, 128 / 128);
    gemm_mfma<64, 128, 32, 64, 1, 128><<<g2, 256, 0, stream>>>(
        rst1h, w2t, feat2h, al2, ar2, el2, er2, N_NODES, 128, 512);
    node_aggr_h<1, 128, 16, false><<<((N_NODES + 63) / 64) * 8, 256, 0, stream>>>(
        feat2h, el2, er2, rowptr, esrc, b2, rst2, N_NODES);

    // ===== readout: per-graph mean (segmented, no atomics) =====
    seg_pool_kernel<<<N_GRAPHS, 128, 0, stream>>>(rst2, gstart, out, 128);
}